// Round 8
// baseline (459.402 us; speedup 1.0000x reference)
//
#include <hip/hip_runtime.h>
#include <hip/hip_fp16.h>

// AttentionBlock3D: channel attention. B=4, C=512, N=T*H*W=16384, 8 heads, d=64.
// Algebraic reduction: result = x + M*H + c, with
//   G = H H^T (per batch, SYMMETRIC -> upper tiles only + k_symm mirror),
//   logits = scale*(Wq G Wk^T + rank-1), P = softmax per head,
//   M = out_w * blockdiag(P) * Wv, c = out_w * blockdiag(P) * bv + out_b.
//
// MFMA kernels use the measured-best geometry (R2): BK=64 (128B rows, 8x16B
// slots, XOR-swizzle slot^(row&7) => 0 bank conflicts), single LDS buffer
// (32 KiB => 4-5 blocks/CU), 2 barriers per K-step. BK=32 variants (R7)
// produce 4-way ds_read conflicts; 64KB dbuf (R6) halves occupancy.

#define CCH 512
#define NTOK 16384
#define NHEAD 8

typedef _Float16 f16;
typedef _Float16 f16x8 __attribute__((ext_vector_type(8)));
typedef float f32x4 __attribute__((ext_vector_type(4)));

__device__ __forceinline__ void g2l16(const void* g, void* l) {
  __builtin_amdgcn_global_load_lds((const __attribute__((address_space(1))) void*)g,
                                   (__attribute__((address_space(3))) void*)l,
                                   16, 0, 0);
}

// ---------------- K1: GroupNorm stats (sum, sumsq) per (b, group) ----------------
__global__ __launch_bounds__(256) void k_stats(const float* __restrict__ x,
                                               float* __restrict__ stats) {
  int bg = blockIdx.y;          // b*8 + g  (group region is contiguous: 64 rows * NTOK)
  int chunk = blockIdx.x;       // 0..31
  const float4* p = (const float4*)(x + (size_t)bg * (64ull * NTOK)) + (size_t)chunk * 8192;
  float s = 0.f, q = 0.f;
  for (int i = threadIdx.x; i < 8192; i += 256) {
    float4 v = p[i];
    s += v.x + v.y + v.z + v.w;
    q += v.x * v.x + v.y * v.y + v.z * v.z + v.w * v.w;
  }
  for (int off = 32; off; off >>= 1) { s += __shfl_down(s, off); q += __shfl_down(q, off); }
  __shared__ float ls[4], lq[4];
  int wid = threadIdx.x >> 6, lane = threadIdx.x & 63;
  if (lane == 0) { ls[wid] = s; lq[wid] = q; }
  __syncthreads();
  if (threadIdx.x == 0) {
    atomicAdd(&stats[bg * 2 + 0], ls[0] + ls[1] + ls[2] + ls[3]);
    atomicAdd(&stats[bg * 2 + 1], lq[0] + lq[1] + lq[2] + lq[3]);
  }
}

// ---------------- K2: normalize -> H (fp16, [b][c][n]) and Ht (fp16, [b][n][c]), s = H*1 ----
__global__ __launch_bounds__(256) void k_gnorm(const float* __restrict__ x,
                                               const float* __restrict__ gw,
                                               const float* __restrict__ gb,
                                               const float* __restrict__ stats,
                                               f16* __restrict__ H, f16* __restrict__ Ht,
                                               float* __restrict__ svec) {
  int nc = blockIdx.x;   // n chunk (256 tokens)
  int cg = blockIdx.y;   // channel group (64 ch) == GN group
  int b = blockIdx.z;
  int t = threadIdx.x;
  __shared__ f16 T[256][66];   // [n_local][c_local], padded rows (66 halves = 132B)
  float sum = stats[(b * 8 + cg) * 2], sq = stats[(b * 8 + cg) * 2 + 1];
  const float inv = 1.f / (64.f * (float)NTOK);
  float mean = sum * inv;
  float var = fmaxf(sq * inv - mean * mean, 0.f);
  float rsig = rsqrtf(var + 1e-5f);
  int c0 = cg * 64, n0 = nc * 256;
  for (int r = 0; r < 64; ++r) {
    int c = c0 + r;
    float a = gw[c] * rsig;
    float bb = gb[c] - mean * a;
    size_t idx = ((size_t)(b * CCH + c)) * NTOK + n0 + t;
    float h = x[idx] * a + bb;
    f16 hh = (f16)h;
    H[idx] = hh;
    T[t][r] = hh;
  }
  __syncthreads();
  if (t < 64) {                       // token-sum per channel (partial over this n chunk)
    float acc = 0.f;
    for (int n = 0; n < 256; ++n) acc += (float)T[n][t];
    atomicAdd(&svec[b * CCH + c0 + t], acc);
  }
  int s8 = t & 7, rr = t >> 3;        // transpose write-out: 8 threads per Ht row
  for (int it = 0; it < 8; ++it) {
    int n = it * 32 + rr;
    const f16* src = &T[n][s8 * 8];
    uint4 u;
    u.x = *(const unsigned int*)(src + 0);
    u.y = *(const unsigned int*)(src + 2);
    u.z = *(const unsigned int*)(src + 4);
    u.w = *(const unsigned int*)(src + 6);
    *(uint4*)&Ht[((size_t)b * NTOK + n0 + n) * CCH + c0 + s8 * 8] = u;
  }
}

// ---------------- K3: G = H H^T, upper tiles, split-K=16, BK=64 single-buf (32KB) ----
#define SPLITS 16
__global__ __launch_bounds__(256, 4) void k_syrk(const f16* __restrict__ H,
                                                 float* __restrict__ G) {
  // 10 upper-triangle tiles of 128x128 over the 512x512 output
  const int TI[10] = {0, 0, 0, 0, 1, 1, 1, 2, 2, 3};
  const int TJ[10] = {0, 1, 2, 3, 1, 2, 3, 2, 3, 3};
  int tile = blockIdx.x;
  int split = blockIdx.y;
  int b = blockIdx.z;
  int ii = TI[tile], jj = TJ[tile];
  int m0 = ii * 128, n0 = jj * 128;
  int t = threadIdx.x, lane = t & 63, wid = t >> 6;
  int wr = wid >> 1, wc = wid & 1;
  __shared__ __align__(16) f16 sA[128 * 64];
  __shared__ __align__(16) f16 sB[128 * 64];
  const f16* Hb = H + (size_t)b * CCH * NTOK;
  int k0 = split * (NTOK / SPLITS);     // 1024 per split
  f32x4 acc[4][4] = {};
  int ldsrow = wid * 8 + (lane >> 3);   // 128B rows: 8 lanes/row
  int slot = lane & 7;                  // 16B slot within row
  int lr = lane & 15, lk = lane >> 4;

  const int NS = (NTOK / SPLITS) / 64;  // 16 K-steps of BK=64
  for (int ks = 0; ks < NS; ++ks) {
    int kk0 = k0 + ks * 64;
    __syncthreads();
#pragma unroll
    for (int i = 0; i < 4; ++i) {
      int row = ldsrow + i * 32;
      int cA = ((slot ^ (row & 7)) * 8);  // pre-swizzled global source column
      g2l16(Hb + (size_t)(m0 + row) * NTOK + kk0 + cA, &sA[i * 2048 + wid * 512]);
      g2l16(Hb + (size_t)(n0 + row) * NTOK + kk0 + cA, &sB[i * 2048 + wid * 512]);
    }
    asm volatile("s_waitcnt vmcnt(0)" ::: "memory");
    __syncthreads();
#pragma unroll
    for (int kk = 0; kk < 2; ++kk) {
      f16x8 af[4], bf[4];
#pragma unroll
      for (int mi = 0; mi < 4; ++mi) {
        int row = wr * 64 + mi * 16 + lr;
        int ks8 = (kk * 4 + lk) ^ (row & 7);
        af[mi] = *(const f16x8*)&sA[row * 64 + ks8 * 8];
      }
#pragma unroll
      for (int ni = 0; ni < 4; ++ni) {
        int row = wc * 64 + ni * 16 + lr;
        int ks8 = (kk * 4 + lk) ^ (row & 7);
        bf[ni] = *(const f16x8*)&sB[row * 64 + ks8 * 8];
      }
#pragma unroll
      for (int mi = 0; mi < 4; ++mi)
#pragma unroll
        for (int ni = 0; ni < 4; ++ni)
          acc[mi][ni] = __builtin_amdgcn_mfma_f32_16x16x32_f16(af[mi], bf[ni], acc[mi][ni], 0, 0, 0);
    }
  }

  float* Gb = G + (size_t)b * CCH * CCH;
#pragma unroll
  for (int mi = 0; mi < 4; ++mi)
#pragma unroll
    for (int j = 0; j < 4; ++j) {
      int rr2 = m0 + wr * 64 + mi * 16 + lk * 4 + j;
#pragma unroll
      for (int ni = 0; ni < 4; ++ni) {
        int cc = n0 + wc * 64 + ni * 16 + lr;
        atomicAdd(&Gb[(size_t)rr2 * CCH + cc], acc[mi][ni][j]);   // coalesced rows only
      }
    }
}

// ---------------- K3b: mirror upper off-diag tiles to lower triangle ----------------
__global__ __launch_bounds__(256) void k_symm(float* __restrict__ G) {
  // 6 off-diag 128-tiles x 4 subtiles of 64x64 = 24 subtiles per batch
  const int TI6[6] = {0, 0, 0, 1, 1, 2};
  const int TJ6[6] = {1, 2, 3, 2, 3, 3};
  int bx = blockIdx.x;               // 0..23
  int b = blockIdx.y;
  int t6 = bx >> 2, sub = bx & 3;
  int ib = TI6[t6] * 2 + (sub >> 1); // source 64-row block
  int jb = TJ6[t6] * 2 + (sub & 1);  // source 64-col block
  float* Gb = G + (size_t)b * CCH * CCH;
  __shared__ float s[64][65];
  int t = threadIdx.x;
  int r = t >> 2, cg = (t & 3) * 16;
  const float* src = &Gb[(size_t)(ib * 64 + r) * CCH + jb * 64 + cg];
#pragma unroll
  for (int k = 0; k < 4; ++k) {
    float4 v = *(const float4*)(src + k * 4);
    s[r][cg + k * 4 + 0] = v.x; s[r][cg + k * 4 + 1] = v.y;
    s[r][cg + k * 4 + 2] = v.z; s[r][cg + k * 4 + 3] = v.w;
  }
  __syncthreads();
  float* dst = &Gb[(size_t)(jb * 64 + r) * CCH + ib * 64 + cg];
#pragma unroll
  for (int k = 0; k < 4; ++k) {
    float4 v;
    v.x = s[cg + k * 4 + 0][r]; v.y = s[cg + k * 4 + 1][r];
    v.z = s[cg + k * 4 + 2][r]; v.w = s[cg + k * 4 + 3][r];
    *(float4*)(dst + k * 4) = v;
  }
}

// ---------------- K4a/K4c: fp32 512x512x512 GEMM, C[b] = A @ B[b] ----------------
template <bool HALF_OUT>
__global__ __launch_bounds__(256) void k_sgemm512(const float* __restrict__ A,
                                                  const float* __restrict__ Bm,
                                                  void* __restrict__ Cv,
                                                  size_t strideB, size_t strideC) {
  int n0 = blockIdx.x * 64, m0 = blockIdx.y * 64, b = blockIdx.z;
  const float* Bb = Bm + (size_t)b * strideB;
  int t = threadIdx.x;
  int rm = t >> 4, rn = t & 15;
  __shared__ float sA[16][68];  // [k][m] transposed
  __shared__ float sB[16][68];  // [k][n]
  float acc[4][4] = {};
  for (int k0 = 0; k0 < 512; k0 += 16) {
#pragma unroll
    for (int i = 0; i < 4; ++i) {
      int idx = i * 256 + t;
      int mrow = idx >> 4, kc = idx & 15;
      sA[kc][mrow] = A[(size_t)(m0 + mrow) * CCH + k0 + kc];
      int krow = idx >> 6, ncc = idx & 63;
      sB[krow][ncc] = Bb[(size_t)(k0 + krow) * CCH + n0 + ncc];
    }
    __syncthreads();
#pragma unroll
    for (int k = 0; k < 16; ++k) {
      float4 a4 = *(const float4*)&sA[k][rm * 4];
      float4 b4 = *(const float4*)&sB[k][rn * 4];
      acc[0][0] += a4.x * b4.x; acc[0][1] += a4.x * b4.y; acc[0][2] += a4.x * b4.z; acc[0][3] += a4.x * b4.w;
      acc[1][0] += a4.y * b4.x; acc[1][1] += a4.y * b4.y; acc[1][2] += a4.y * b4.z; acc[1][3] += a4.y * b4.w;
      acc[2][0] += a4.z * b4.x; acc[2][1] += a4.z * b4.y; acc[2][2] += a4.z * b4.z; acc[2][3] += a4.z * b4.w;
      acc[3][0] += a4.w * b4.x; acc[3][1] += a4.w * b4.y; acc[3][2] += a4.w * b4.z; acc[3][3] += a4.w * b4.w;
    }
    __syncthreads();
  }
  if constexpr (HALF_OUT) {
    f16* Cc = ((f16*)Cv) + (size_t)b * strideC;
#pragma unroll
    for (int i = 0; i < 4; ++i)
#pragma unroll
      for (int j = 0; j < 4; ++j)
        Cc[(size_t)(m0 + rm * 4 + i) * CCH + n0 + rn * 4 + j] = (f16)acc[i][j];
  } else {
    float* Cc = ((float*)Cv) + (size_t)b * strideC;
#pragma unroll
    for (int i = 0; i < 4; ++i)
#pragma unroll
      for (int j = 0; j < 4; ++j)
        Cc[(size_t)(m0 + rm * 4 + i) * CCH + n0 + rn * 4 + j] = acc[i][j];
  }
}

// ---------------- K4b-1: uvec[b][0:512]=Wq@s, [512:1024]=Wk@s ----------------
__global__ __launch_bounds__(256) void k_uvec(const float* __restrict__ qkvw,
                                              const float* __restrict__ svec,
                                              float* __restrict__ uvec) {
  int o = blockIdx.x * 256 + threadIdx.x;   // 0..1023
  int b = blockIdx.y;
  __shared__ float ss[512];
  for (int i = threadIdx.x; i < 512; i += 256) ss[i] = svec[b * CCH + i];
  __syncthreads();
  float a = 0.f;
  const float* wr_ = qkvw + (size_t)o * CCH;
  for (int c = 0; c < 512; ++c) a += wr_[c] * ss[c];
  uvec[b * 1024 + o] = a;
}

// ---------------- K4b-2: L[b,h] += T1_h[64xK-chunk] @ Wk_h^T (split-K, atomics) ----
__global__ __launch_bounds__(256) void k_logits(const float* __restrict__ T1,
                                                const float* __restrict__ qkvw,
                                                float* __restrict__ L) {
  int kc = blockIdx.x;     // 8 chunks of 64 k
  int h = blockIdx.y, b = blockIdx.z;
  int t = threadIdx.x;
  int h64 = h * 64, k0 = kc * 64;
  __shared__ float sT[64][68];   // [d][k]
  __shared__ float sW[64][68];   // [k][e]
#pragma unroll
  for (int i = 0; i < 16; ++i) {
    int idx = i * 256 + t;
    int r = idx >> 6, c = idx & 63;
    sT[r][c] = T1[((size_t)b * CCH + h64 + r) * CCH + k0 + c];
    sW[c][r] = qkvw[(size_t)(512 + h64 + r) * CCH + k0 + c];
  }
  __syncthreads();
  int d = t >> 2, eg = (t & 3) * 16;
  float acc[16] = {};
  for (int k = 0; k < 64; ++k) {
    float a = sT[d][k];
    float4 w0 = *(const float4*)&sW[k][eg];
    float4 w1 = *(const float4*)&sW[k][eg + 4];
    float4 w2 = *(const float4*)&sW[k][eg + 8];
    float4 w3 = *(const float4*)&sW[k][eg + 12];
    acc[0] += a * w0.x;  acc[1] += a * w0.y;  acc[2] += a * w0.z;  acc[3] += a * w0.w;
    acc[4] += a * w1.x;  acc[5] += a * w1.y;  acc[6] += a * w1.z;  acc[7] += a * w1.w;
    acc[8] += a * w2.x;  acc[9] += a * w2.y;  acc[10] += a * w2.z; acc[11] += a * w2.w;
    acc[12] += a * w3.x; acc[13] += a * w3.y; acc[14] += a * w3.z; acc[15] += a * w3.w;
  }
  float* Lrow = &L[(((size_t)b * NHEAD + h) * 64 + d) * 64 + eg];
#pragma unroll
  for (int i = 0; i < 16; ++i) atomicAdd(&Lrow[i], acc[i]);
}

// ---------------- K4b-3: softmax rows + rank-1 bias terms -> P, pbv ----------------
__global__ __launch_bounds__(64) void k_softmax(const float* __restrict__ L,
                                                const float* __restrict__ uvec,
                                                const float* __restrict__ qkvb,
                                                float* __restrict__ P,
                                                float* __restrict__ pbv) {
  int bh = blockIdx.x;           // b*8 + h
  int b = bh >> 3, h = bh & 7;
  int d = threadIdx.x;           // 0..63
  int h64 = h * 64;
  __shared__ float sbk[64], sbv[64], suk[64];
  sbk[d] = qkvb[512 + h64 + d];
  sbv[d] = qkvb[1024 + h64 + d];
  suk[d] = uvec[b * 1024 + 512 + h64 + d];
  __syncthreads();
  float uq = uvec[b * 1024 + h64 + d];
  float bq = qkvb[h64 + d];
  float l[64];
  const float* Lr = &L[((size_t)bh * 64 + d) * 64];
  float m = -1e30f;
#pragma unroll
  for (int e = 0; e < 64; ++e) {
    float v = (Lr[e] + uq * sbk[e] + bq * suk[e] + 16384.f * bq * sbk[e]) * 0.125f;
    l[e] = v;
    m = fmaxf(m, v);
  }
  float sum = 0.f;
#pragma unroll
  for (int e = 0; e < 64; ++e) { float p = expf(l[e] - m); l[e] = p; sum += p; }
  float r = 1.f / sum, pb = 0.f;
  float* Pr = &P[((size_t)bh * 64 + d) * 64];
#pragma unroll
  for (int e = 0; e < 64; ++e) { float p = l[e] * r; Pr[e] = p; pb += p * sbv[e]; }
  pbv[b * CCH + h64 + d] = pb;
}

// ---------------- K4b-4: R[b, h64+d, c] = sum_e P[b,h,d,e] Wv[h64+e][c] ----------
__global__ __launch_bounds__(256) void k_pv(const float* __restrict__ P,
                                            const float* __restrict__ qkvw,
                                            float* __restrict__ R) {
  int ct = blockIdx.x;     // 8 c-tiles of 64
  int h = blockIdx.y, b = blockIdx.z;
  int t = threadIdx.x;
  int h64 = h * 64, c0 = ct * 64;
  __shared__ float sP[64][68];   // [d][e]
  __shared__ float sW[64][68];   // [e][c]
#pragma unroll
  for (int i = 0; i < 16; ++i) {
    int idx = i * 256 + t;
    int r = idx >> 6, c = idx & 63;
    sP[r][c] = P[(((size_t)b * NHEAD + h) * 64 + r) * 64 + c];
    sW[r][c] = qkvw[(size_t)(1024 + h64 + r) * CCH + c0 + c];
  }
  __syncthreads();
  int d = t >> 2, cg = (t & 3) * 16;
  float r0 = 0, r1 = 0, r2 = 0, r3 = 0, r4 = 0, r5 = 0, r6 = 0, r7 = 0;
  float r8 = 0, r9 = 0, r10 = 0, r11 = 0, r12 = 0, r13 = 0, r14 = 0, r15 = 0;
  for (int e = 0; e < 64; ++e) {
    float p = sP[d][e];
    float4 w0 = *(const float4*)&sW[e][cg];
    float4 w1 = *(const float4*)&sW[e][cg + 4];
    float4 w2 = *(const float4*)&sW[e][cg + 8];
    float4 w3 = *(const float4*)&sW[e][cg + 12];
    r0 += p * w0.x;  r1 += p * w0.y;  r2 += p * w0.z;  r3 += p * w0.w;
    r4 += p * w1.x;  r5 += p * w1.y;  r6 += p * w1.z;  r7 += p * w1.w;
    r8 += p * w2.x;  r9 += p * w2.y;  r10 += p * w2.z; r11 += p * w2.w;
    r12 += p * w3.x; r13 += p * w3.y; r14 += p * w3.z; r15 += p * w3.w;
  }
  float* Rrow = &R[((size_t)b * CCH + h64 + d) * CCH + c0];
  *(float4*)&Rrow[cg + 0]  = make_float4(r0, r1, r2, r3);
  *(float4*)&Rrow[cg + 4]  = make_float4(r4, r5, r6, r7);
  *(float4*)&Rrow[cg + 8]  = make_float4(r8, r9, r10, r11);
  *(float4*)&Rrow[cg + 12] = make_float4(r12, r13, r14, r15);
}

// ---------------- K4d: cvec = out_w @ pbv + out_b ----------------
__global__ __launch_bounds__(256) void k_cvec(const float* __restrict__ outw,
                                              const float* __restrict__ outb,
                                              const float* __restrict__ pbv,
                                              float* __restrict__ cvec) {
  int o = blockIdx.x * 256 + threadIdx.x;
  int b = blockIdx.y;
  __shared__ float sp[512];
  for (int i = threadIdx.x; i < 512; i += 256) sp[i] = pbv[b * CCH + i];
  __syncthreads();
  float a = outb[o];
  const float* wr_ = outw + (size_t)o * CCH;
  for (int c2 = 0; c2 < 512; ++c2) a += wr_[c2] * sp[c2];
  cvec[b * CCH + o] = a;
}

// ---------------- K5: out = x + M16 @ H + cvec (fp16 MFMA, BK=64 single-buf) -------
__global__ __launch_bounds__(256, 4) void k_out(const f16* __restrict__ M16,
                                                const f16* __restrict__ Ht,
                                                const float* __restrict__ x,
                                                const float* __restrict__ cvec,
                                                float* __restrict__ out) {
  int nt = blockIdx.x;   // 128 n-tiles
  int mt = blockIdx.y;   // 4 o-tiles
  int b = blockIdx.z;
  int m0 = mt * 128, n0 = nt * 128;
  int t = threadIdx.x, lane = t & 63, wid = t >> 6;
  int wr = wid >> 1, wc = wid & 1;
  __shared__ __align__(16) f16 sA[128 * 64];
  __shared__ __align__(16) f16 sB[128 * 64];
  const f16* A = M16 + (size_t)b * CCH * CCH;
  const f16* Bp = Ht + (size_t)b * NTOK * CCH;
  f32x4 acc[4][4] = {};
  int ldsrow = wid * 8 + (lane >> 3);
  int slot = lane & 7;
  int lr = lane & 15, lk = lane >> 4;
  for (int ks = 0; ks < 8; ++ks) {
    int kk0 = ks * 64;
    __syncthreads();
#pragma unroll
    for (int i = 0; i < 4; ++i) {
      int row = ldsrow + i * 32;
      int cA = ((slot ^ (row & 7)) * 8);
      g2l16(A + (size_t)(m0 + row) * CCH + kk0 + cA, &sA[i * 2048 + wid * 512]);
      g2l16(Bp + (size_t)(n0 + row) * CCH + kk0 + cA, &sB[i * 2048 + wid * 512]);
    }
    asm volatile("s_waitcnt vmcnt(0)" ::: "memory");
    __syncthreads();
#pragma unroll
    for (int kk = 0; kk < 2; ++kk) {
      f16x8 af[4], bf[4];
#pragma unroll
      for (int mi = 0; mi < 4; ++mi) {
        int row = wr * 64 + mi * 16 + lr;
        int ks8 = (kk * 4 + lk) ^ (row & 7);
        af[mi] = *(const f16x8*)&sA[row * 64 + ks8 * 8];
      }
#pragma unroll
      for (int ni = 0; ni < 4; ++ni) {
        int row = wc * 64 + ni * 16 + lr;
        int ks8 = (kk * 4 + lk) ^ (row & 7);
        bf[ni] = *(const f16x8*)&sB[row * 64 + ks8 * 8];
      }
#pragma unroll
      for (int mi = 0; mi < 4; ++mi)
#pragma unroll
        for (int ni = 0; ni < 4; ++ni)
          acc[mi][ni] = __builtin_amdgcn_mfma_f32_16x16x32_f16(af[mi], bf[ni], acc[mi][ni], 0, 0, 0);
    }
  }

  const float* xb = x + ((size_t)b * CCH) * NTOK;
  float* ob = out + ((size_t)b * CCH) * NTOK;
#pragma unroll
  for (int mi = 0; mi < 4; ++mi)
#pragma unroll
    for (int j = 0; j < 4; ++j) {
      int o = m0 + wr * 64 + mi * 16 + lk * 4 + j;
      float cv = cvec[b * CCH + o];
      size_t rowoff = (size_t)o * NTOK;
#pragma unroll
      for (int ni = 0; ni < 4; ++ni) {
        int n = n0 + wc * 64 + ni * 16 + lr;
        size_t idx = rowoff + n;
        ob[idx] = xb[idx] + acc[mi][ni][j] + cv;
      }
    }
}

extern "C" void kernel_launch(void* const* d_in, const int* in_sizes, int n_in,
                              void* d_out, int out_size, void* d_ws, size_t ws_size,
                              hipStream_t stream) {
  const float* x    = (const float*)d_in[0];
  const float* gw   = (const float*)d_in[1];
  const float* gb   = (const float*)d_in[2];
  const float* qkvw = (const float*)d_in[3];
  const float* qkvb = (const float*)d_in[4];
  const float* outw = (const float*)d_in[5];
  const float* outb = (const float*)d_in[6];
  int B = in_sizes[0] / (CCH * NTOK);   // 4

  char* ws = (char*)d_ws;
  size_t off = 0;
  f16* H    = (f16*)(ws + off);   off += (size_t)B * CCH * NTOK * 2;   // 64 MiB
  f16* Ht   = (f16*)(ws + off);   off += (size_t)B * NTOK * CCH * 2;   // 64 MiB
  float* G  = (float*)(ws + off); off += (size_t)B * CCH * CCH * 4;    // 4 MiB
  float* T1 = (float*)(ws + off); off += (size_t)B * CCH * CCH * 4;    // 4 MiB
  float* R  = (float*)(ws + off); off += (size_t)B * CCH * CCH * 4;    // 4 MiB
  f16* M16  = (f16*)(ws + off);   off += (size_t)B * CCH * CCH * 2;    // 2 MiB
  float* P  = (float*)(ws + off); off += (size_t)B * NHEAD * 64 * 64 * 4;  // 512 KiB
  float* uvec  = (float*)(ws + off); off += (size_t)B * 1024 * 4;
  float* pbv   = (float*)(ws + off); off += (size_t)B * CCH * 4;
  float* cvec  = (float*)(ws + off); off += (size_t)B * CCH * 4;
  // zero-init region: stats, svec, L (contiguous -> single memset)
  float* stats = (float*)(ws + off); off += (size_t)B * 8 * 2 * 4;
  float* svec  = (float*)(ws + off); off += (size_t)B * CCH * 4;
  float* L     = (float*)(ws + off); off += (size_t)B * NHEAD * 64 * 64 * 4;  // 512 KiB
  size_t zbytes = (size_t)(B * 8 * 2 + B * CCH + B * NHEAD * 64 * 64) * 4;

  hipMemsetAsync(G, 0, (size_t)B * CCH * CCH * 4, stream);
  hipMemsetAsync(stats, 0, zbytes, stream);

  k_stats<<<dim3(32, B * 8), 256, 0, stream>>>(x, stats);
  k_gnorm<<<dim3(64, 8, B), 256, 0, stream>>>(x, gw, gb, stats, H, Ht, svec);
  k_syrk<<<dim3(10, SPLITS, B), 256, 0, stream>>>(H, G);
  k_symm<<<dim3(24, B), 256, 0, stream>>>(G);
  k_sgemm512<false><<<dim3(8, 8, B), 256, 0, stream>>>(qkvw, G, T1,
                                                       (size_t)CCH * CCH, (size_t)CCH * CCH);
  k_uvec<<<dim3(4, B), 256, 0, stream>>>(qkvw, svec, uvec);
  k_logits<<<dim3(8, NHEAD, B), 256, 0, stream>>>(T1, qkvw, L);
  k_softmax<<<dim3(B * NHEAD), 64, 0, stream>>>(L, uvec, qkvb, P, pbv);
  k_pv<<<dim3(8, NHEAD, B), 256, 0, stream>>>(P, qkvw, R);
  k_sgemm512<true><<<dim3(8, 8, B), 256, 0, stream>>>(outw, R, M16,
                                                      (size_t)CCH * CCH, (size_t)CCH * CCH);
  k_cvec<<<dim3(2, B), 256, 0, stream>>>(outw, outb, pbv, cvec);
  k_out<<<dim3(128, 4, B), 256, 0, stream>>>(M16, Ht, x, cvec, (float*)d_out);
}

// Round 9
// 421.562 us; speedup vs baseline: 1.0898x; 1.0898x over previous
//
#include <hip/hip_runtime.h>
#include <hip/hip_fp16.h>

// AttentionBlock3D: channel attention. B=4, C=512, N=T*H*W=16384, 8 heads, d=64.
// Algebraic reduction: result = x + M*H + c, with
//   G = H H^T (per batch, SYMMETRIC -> upper tiles only + k_symm mirror),
//   logits = scale*(Wq G Wk^T + rank-1), P = softmax per head,
//   M = out_w * blockdiag(P) * Wv, c = out_w * blockdiag(P) * bv + out_b.
//
// MFMA kernel geometry (measured-best, R2/R8/R9 ladder):
//   BK=64 (128B rows, 8x16B slots, XOR-swizzle slot^(row&7) => 0 bank conflicts),
//   single LDS buffer (32 KiB), 2 barriers per K-step,
//   __launch_bounds__(256, 2): lb(256,4) packs 4-5 blocks/CU and REGRESSES 39%
//   (R8: 118us vs R2: 85us, same code otherwise) - barrier-drain convoying.
//   BK=32 variants (R7) produce 4-way ds_read conflicts; 64KB dbuf (R6) halves occupancy.

#define CCH 512
#define NTOK 16384
#define NHEAD 8

typedef _Float16 f16;
typedef _Float16 f16x8 __attribute__((ext_vector_type(8)));
typedef float f32x4 __attribute__((ext_vector_type(4)));

__device__ __forceinline__ void g2l16(const void* g, void* l) {
  __builtin_amdgcn_global_load_lds((const __attribute__((address_space(1))) void*)g,
                                   (__attribute__((address_space(3))) void*)l,
                                   16, 0, 0);
}

// ---------------- K1: GroupNorm stats (sum, sumsq) per (b, group) ----------------
__global__ __launch_bounds__(256) void k_stats(const float* __restrict__ x,
                                               float* __restrict__ stats) {
  int bg = blockIdx.y;          // b*8 + g  (group region is contiguous: 64 rows * NTOK)
  int chunk = blockIdx.x;       // 0..31
  const float4* p = (const float4*)(x + (size_t)bg * (64ull * NTOK)) + (size_t)chunk * 8192;
  float s = 0.f, q = 0.f;
  for (int i = threadIdx.x; i < 8192; i += 256) {
    float4 v = p[i];
    s += v.x + v.y + v.z + v.w;
    q += v.x * v.x + v.y * v.y + v.z * v.z + v.w * v.w;
  }
  for (int off = 32; off; off >>= 1) { s += __shfl_down(s, off); q += __shfl_down(q, off); }
  __shared__ float ls[4], lq[4];
  int wid = threadIdx.x >> 6, lane = threadIdx.x & 63;
  if (lane == 0) { ls[wid] = s; lq[wid] = q; }
  __syncthreads();
  if (threadIdx.x == 0) {
    atomicAdd(&stats[bg * 2 + 0], ls[0] + ls[1] + ls[2] + ls[3]);
    atomicAdd(&stats[bg * 2 + 1], lq[0] + lq[1] + lq[2] + lq[3]);
  }
}

// ---------------- K2: normalize -> H (fp16, [b][c][n]) and Ht (fp16, [b][n][c]), s = H*1 ----
__global__ __launch_bounds__(256) void k_gnorm(const float* __restrict__ x,
                                               const float* __restrict__ gw,
                                               const float* __restrict__ gb,
                                               const float* __restrict__ stats,
                                               f16* __restrict__ H, f16* __restrict__ Ht,
                                               float* __restrict__ svec) {
  int nc = blockIdx.x;   // n chunk (256 tokens)
  int cg = blockIdx.y;   // channel group (64 ch) == GN group
  int b = blockIdx.z;
  int t = threadIdx.x;
  __shared__ f16 T[256][66];   // [n_local][c_local], padded rows (66 halves = 132B)
  float sum = stats[(b * 8 + cg) * 2], sq = stats[(b * 8 + cg) * 2 + 1];
  const float inv = 1.f / (64.f * (float)NTOK);
  float mean = sum * inv;
  float var = fmaxf(sq * inv - mean * mean, 0.f);
  float rsig = rsqrtf(var + 1e-5f);
  int c0 = cg * 64, n0 = nc * 256;
  for (int r = 0; r < 64; ++r) {
    int c = c0 + r;
    float a = gw[c] * rsig;
    float bb = gb[c] - mean * a;
    size_t idx = ((size_t)(b * CCH + c)) * NTOK + n0 + t;
    float h = x[idx] * a + bb;
    f16 hh = (f16)h;
    H[idx] = hh;
    T[t][r] = hh;
  }
  __syncthreads();
  if (t < 64) {                       // token-sum per channel (partial over this n chunk)
    float acc = 0.f;
    for (int n = 0; n < 256; ++n) acc += (float)T[n][t];
    atomicAdd(&svec[b * CCH + c0 + t], acc);
  }
  int s8 = t & 7, rr = t >> 3;        // transpose write-out: 8 threads per Ht row
  for (int it = 0; it < 8; ++it) {
    int n = it * 32 + rr;
    const f16* src = &T[n][s8 * 8];
    uint4 u;
    u.x = *(const unsigned int*)(src + 0);
    u.y = *(const unsigned int*)(src + 2);
    u.z = *(const unsigned int*)(src + 4);
    u.w = *(const unsigned int*)(src + 6);
    *(uint4*)&Ht[((size_t)b * NTOK + n0 + n) * CCH + c0 + s8 * 8] = u;
  }
}

// ---------------- K3: G = H H^T, upper tiles, split-K=16, BK=64 single-buf (32KB) ----
#define SPLITS 16
__global__ __launch_bounds__(256, 2) void k_syrk(const f16* __restrict__ H,
                                                 float* __restrict__ G) {
  // 10 upper-triangle tiles of 128x128 over the 512x512 output
  const int TI[10] = {0, 0, 0, 0, 1, 1, 1, 2, 2, 3};
  const int TJ[10] = {0, 1, 2, 3, 1, 2, 3, 2, 3, 3};
  int tile = blockIdx.x;
  int split = blockIdx.y;
  int b = blockIdx.z;
  int ii = TI[tile], jj = TJ[tile];
  int m0 = ii * 128, n0 = jj * 128;
  int t = threadIdx.x, lane = t & 63, wid = t >> 6;
  int wr = wid >> 1, wc = wid & 1;
  __shared__ __align__(16) f16 sA[128 * 64];
  __shared__ __align__(16) f16 sB[128 * 64];
  const f16* Hb = H + (size_t)b * CCH * NTOK;
  int k0 = split * (NTOK / SPLITS);     // 1024 per split
  f32x4 acc[4][4] = {};
  int ldsrow = wid * 8 + (lane >> 3);   // 128B rows: 8 lanes/row
  int slot = lane & 7;                  // 16B slot within row
  int lr = lane & 15, lk = lane >> 4;

  const int NS = (NTOK / SPLITS) / 64;  // 16 K-steps of BK=64
  for (int ks = 0; ks < NS; ++ks) {
    int kk0 = k0 + ks * 64;
    __syncthreads();
#pragma unroll
    for (int i = 0; i < 4; ++i) {
      int row = ldsrow + i * 32;
      int cA = ((slot ^ (row & 7)) * 8);  // pre-swizzled global source column
      g2l16(Hb + (size_t)(m0 + row) * NTOK + kk0 + cA, &sA[i * 2048 + wid * 512]);
      g2l16(Hb + (size_t)(n0 + row) * NTOK + kk0 + cA, &sB[i * 2048 + wid * 512]);
    }
    asm volatile("s_waitcnt vmcnt(0)" ::: "memory");
    __syncthreads();
#pragma unroll
    for (int kk = 0; kk < 2; ++kk) {
      f16x8 af[4], bf[4];
#pragma unroll
      for (int mi = 0; mi < 4; ++mi) {
        int row = wr * 64 + mi * 16 + lr;
        int ks8 = (kk * 4 + lk) ^ (row & 7);
        af[mi] = *(const f16x8*)&sA[row * 64 + ks8 * 8];
      }
#pragma unroll
      for (int ni = 0; ni < 4; ++ni) {
        int row = wc * 64 + ni * 16 + lr;
        int ks8 = (kk * 4 + lk) ^ (row & 7);
        bf[ni] = *(const f16x8*)&sB[row * 64 + ks8 * 8];
      }
#pragma unroll
      for (int mi = 0; mi < 4; ++mi)
#pragma unroll
        for (int ni = 0; ni < 4; ++ni)
          acc[mi][ni] = __builtin_amdgcn_mfma_f32_16x16x32_f16(af[mi], bf[ni], acc[mi][ni], 0, 0, 0);
    }
  }

  float* Gb = G + (size_t)b * CCH * CCH;
#pragma unroll
  for (int mi = 0; mi < 4; ++mi)
#pragma unroll
    for (int j = 0; j < 4; ++j) {
      int rr2 = m0 + wr * 64 + mi * 16 + lk * 4 + j;
#pragma unroll
      for (int ni = 0; ni < 4; ++ni) {
        int cc = n0 + wc * 64 + ni * 16 + lr;
        atomicAdd(&Gb[(size_t)rr2 * CCH + cc], acc[mi][ni][j]);   // coalesced rows only
      }
    }
}

// ---------------- K3b: mirror upper off-diag tiles to lower triangle ----------------
__global__ __launch_bounds__(256) void k_symm(float* __restrict__ G) {
  // 6 off-diag 128-tiles x 4 subtiles of 64x64 = 24 subtiles per batch
  const int TI6[6] = {0, 0, 0, 1, 1, 2};
  const int TJ6[6] = {1, 2, 3, 2, 3, 3};
  int bx = blockIdx.x;               // 0..23
  int b = blockIdx.y;
  int t6 = bx >> 2, sub = bx & 3;
  int ib = TI6[t6] * 2 + (sub >> 1); // source 64-row block
  int jb = TJ6[t6] * 2 + (sub & 1);  // source 64-col block
  float* Gb = G + (size_t)b * CCH * CCH;
  __shared__ float s[64][65];
  int t = threadIdx.x;
  int r = t >> 2, cg = (t & 3) * 16;
  const float* src = &Gb[(size_t)(ib * 64 + r) * CCH + jb * 64 + cg];
#pragma unroll
  for (int k = 0; k < 4; ++k) {
    float4 v = *(const float4*)(src + k * 4);
    s[r][cg + k * 4 + 0] = v.x; s[r][cg + k * 4 + 1] = v.y;
    s[r][cg + k * 4 + 2] = v.z; s[r][cg + k * 4 + 3] = v.w;
  }
  __syncthreads();
  float* dst = &Gb[(size_t)(jb * 64 + r) * CCH + ib * 64 + cg];
#pragma unroll
  for (int k = 0; k < 4; ++k) {
    float4 v;
    v.x = s[cg + k * 4 + 0][r]; v.y = s[cg + k * 4 + 1][r];
    v.z = s[cg + k * 4 + 2][r]; v.w = s[cg + k * 4 + 3][r];
    *(float4*)(dst + k * 4) = v;
  }
}

// ---------------- K4a/K4c: fp32 512x512x512 GEMM, C[b] = A @ B[b] ----------------
template <bool HALF_OUT>
__global__ __launch_bounds__(256) void k_sgemm512(const float* __restrict__ A,
                                                  const float* __restrict__ Bm,
                                                  void* __restrict__ Cv,
                                                  size_t strideB, size_t strideC) {
  int n0 = blockIdx.x * 64, m0 = blockIdx.y * 64, b = blockIdx.z;
  const float* Bb = Bm + (size_t)b * strideB;
  int t = threadIdx.x;
  int rm = t >> 4, rn = t & 15;
  __shared__ float sA[16][68];  // [k][m] transposed
  __shared__ float sB[16][68];  // [k][n]
  float acc[4][4] = {};
  for (int k0 = 0; k0 < 512; k0 += 16) {
#pragma unroll
    for (int i = 0; i < 4; ++i) {
      int idx = i * 256 + t;
      int mrow = idx >> 4, kc = idx & 15;
      sA[kc][mrow] = A[(size_t)(m0 + mrow) * CCH + k0 + kc];
      int krow = idx >> 6, ncc = idx & 63;
      sB[krow][ncc] = Bb[(size_t)(k0 + krow) * CCH + n0 + ncc];
    }
    __syncthreads();
#pragma unroll
    for (int k = 0; k < 16; ++k) {
      float4 a4 = *(const float4*)&sA[k][rm * 4];
      float4 b4 = *(const float4*)&sB[k][rn * 4];
      acc[0][0] += a4.x * b4.x; acc[0][1] += a4.x * b4.y; acc[0][2] += a4.x * b4.z; acc[0][3] += a4.x * b4.w;
      acc[1][0] += a4.y * b4.x; acc[1][1] += a4.y * b4.y; acc[1][2] += a4.y * b4.z; acc[1][3] += a4.y * b4.w;
      acc[2][0] += a4.z * b4.x; acc[2][1] += a4.z * b4.y; acc[2][2] += a4.z * b4.z; acc[2][3] += a4.z * b4.w;
      acc[3][0] += a4.w * b4.x; acc[3][1] += a4.w * b4.y; acc[3][2] += a4.w * b4.z; acc[3][3] += a4.w * b4.w;
    }
    __syncthreads();
  }
  if constexpr (HALF_OUT) {
    f16* Cc = ((f16*)Cv) + (size_t)b * strideC;
#pragma unroll
    for (int i = 0; i < 4; ++i)
#pragma unroll
      for (int j = 0; j < 4; ++j)
        Cc[(size_t)(m0 + rm * 4 + i) * CCH + n0 + rn * 4 + j] = (f16)acc[i][j];
  } else {
    float* Cc = ((float*)Cv) + (size_t)b * strideC;
#pragma unroll
    for (int i = 0; i < 4; ++i)
#pragma unroll
      for (int j = 0; j < 4; ++j)
        Cc[(size_t)(m0 + rm * 4 + i) * CCH + n0 + rn * 4 + j] = acc[i][j];
  }
}

// ---------------- K4b-1: uvec[b][0:512]=Wq@s, [512:1024]=Wk@s ----------------
__global__ __launch_bounds__(256) void k_uvec(const float* __restrict__ qkvw,
                                              const float* __restrict__ svec,
                                              float* __restrict__ uvec) {
  int o = blockIdx.x * 256 + threadIdx.x;   // 0..1023
  int b = blockIdx.y;
  __shared__ float ss[512];
  for (int i = threadIdx.x; i < 512; i += 256) ss[i] = svec[b * CCH + i];
  __syncthreads();
  float a = 0.f;
  const float* wr_ = qkvw + (size_t)o * CCH;
  for (int c = 0; c < 512; ++c) a += wr_[c] * ss[c];
  uvec[b * 1024 + o] = a;
}

// ---------------- K4b-2: L[b,h] += T1_h[64xK-chunk] @ Wk_h^T (split-K, atomics) ----
__global__ __launch_bounds__(256) void k_logits(const float* __restrict__ T1,
                                                const float* __restrict__ qkvw,
                                                float* __restrict__ L) {
  int kc = blockIdx.x;     // 8 chunks of 64 k
  int h = blockIdx.y, b = blockIdx.z;
  int t = threadIdx.x;
  int h64 = h * 64, k0 = kc * 64;
  __shared__ float sT[64][68];   // [d][k]
  __shared__ float sW[64][68];   // [k][e]
#pragma unroll
  for (int i = 0; i < 16; ++i) {
    int idx = i * 256 + t;
    int r = idx >> 6, c = idx & 63;
    sT[r][c] = T1[((size_t)b * CCH + h64 + r) * CCH + k0 + c];
    sW[c][r] = qkvw[(size_t)(512 + h64 + r) * CCH + k0 + c];
  }
  __syncthreads();
  int d = t >> 2, eg = (t & 3) * 16;
  float acc[16] = {};
  for (int k = 0; k < 64; ++k) {
    float a = sT[d][k];
    float4 w0 = *(const float4*)&sW[k][eg];
    float4 w1 = *(const float4*)&sW[k][eg + 4];
    float4 w2 = *(const float4*)&sW[k][eg + 8];
    float4 w3 = *(const float4*)&sW[k][eg + 12];
    acc[0] += a * w0.x;  acc[1] += a * w0.y;  acc[2] += a * w0.z;  acc[3] += a * w0.w;
    acc[4] += a * w1.x;  acc[5] += a * w1.y;  acc[6] += a * w1.z;  acc[7] += a * w1.w;
    acc[8] += a * w2.x;  acc[9] += a * w2.y;  acc[10] += a * w2.z; acc[11] += a * w2.w;
    acc[12] += a * w3.x; acc[13] += a * w3.y; acc[14] += a * w3.z; acc[15] += a * w3.w;
  }
  float* Lrow = &L[(((size_t)b * NHEAD + h) * 64 + d) * 64 + eg];
#pragma unroll
  for (int i = 0; i < 16; ++i) atomicAdd(&Lrow[i], acc[i]);
}

// ---------------- K4b-3: softmax rows + rank-1 bias terms -> P, pbv ----------------
__global__ __launch_bounds__(64) void k_softmax(const float* __restrict__ L,
                                                const float* __restrict__ uvec,
                                                const float* __restrict__ qkvb,
                                                float* __restrict__ P,
                                                float* __restrict__ pbv) {
  int bh = blockIdx.x;           // b*8 + h
  int b = bh >> 3, h = bh & 7;
  int d = threadIdx.x;           // 0..63
  int h64 = h * 64;
  __shared__ float sbk[64], sbv[64], suk[64];
  sbk[d] = qkvb[512 + h64 + d];
  sbv[d] = qkvb[1024 + h64 + d];
  suk[d] = uvec[b * 1024 + 512 + h64 + d];
  __syncthreads();
  float uq = uvec[b * 1024 + h64 + d];
  float bq = qkvb[h64 + d];
  float l[64];
  const float* Lr = &L[((size_t)bh * 64 + d) * 64];
  float m = -1e30f;
#pragma unroll
  for (int e = 0; e < 64; ++e) {
    float v = (Lr[e] + uq * sbk[e] + bq * suk[e] + 16384.f * bq * sbk[e]) * 0.125f;
    l[e] = v;
    m = fmaxf(m, v);
  }
  float sum = 0.f;
#pragma unroll
  for (int e = 0; e < 64; ++e) { float p = expf(l[e] - m); l[e] = p; sum += p; }
  float r = 1.f / sum, pb = 0.f;
  float* Pr = &P[((size_t)bh * 64 + d) * 64];
#pragma unroll
  for (int e = 0; e < 64; ++e) { float p = l[e] * r; Pr[e] = p; pb += p * sbv[e]; }
  pbv[b * CCH + h64 + d] = pb;
}

// ---------------- K4b-4: R[b, h64+d, c] = sum_e P[b,h,d,e] Wv[h64+e][c] ----------
__global__ __launch_bounds__(256) void k_pv(const float* __restrict__ P,
                                            const float* __restrict__ qkvw,
                                            float* __restrict__ R) {
  int ct = blockIdx.x;     // 8 c-tiles of 64
  int h = blockIdx.y, b = blockIdx.z;
  int t = threadIdx.x;
  int h64 = h * 64, c0 = ct * 64;
  __shared__ float sP[64][68];   // [d][e]
  __shared__ float sW[64][68];   // [e][c]
#pragma unroll
  for (int i = 0; i < 16; ++i) {
    int idx = i * 256 + t;
    int r = idx >> 6, c = idx & 63;
    sP[r][c] = P[(((size_t)b * NHEAD + h) * 64 + r) * 64 + c];
    sW[r][c] = qkvw[(size_t)(1024 + h64 + r) * CCH + c0 + c];
  }
  __syncthreads();
  int d = t >> 2, cg = (t & 3) * 16;
  float r0 = 0, r1 = 0, r2 = 0, r3 = 0, r4 = 0, r5 = 0, r6 = 0, r7 = 0;
  float r8 = 0, r9 = 0, r10 = 0, r11 = 0, r12 = 0, r13 = 0, r14 = 0, r15 = 0;
  for (int e = 0; e < 64; ++e) {
    float p = sP[d][e];
    float4 w0 = *(const float4*)&sW[e][cg];
    float4 w1 = *(const float4*)&sW[e][cg + 4];
    float4 w2 = *(const float4*)&sW[e][cg + 8];
    float4 w3 = *(const float4*)&sW[e][cg + 12];
    r0 += p * w0.x;  r1 += p * w0.y;  r2 += p * w0.z;  r3 += p * w0.w;
    r4 += p * w1.x;  r5 += p * w1.y;  r6 += p * w1.z;  r7 += p * w1.w;
    r8 += p * w2.x;  r9 += p * w2.y;  r10 += p * w2.z; r11 += p * w2.w;
    r12 += p * w3.x; r13 += p * w3.y; r14 += p * w3.z; r15 += p * w3.w;
  }
  float* Rrow = &R[((size_t)b * CCH + h64 + d) * CCH + c0];
  *(float4*)&Rrow[cg + 0]  = make_float4(r0, r1, r2, r3);
  *(float4*)&Rrow[cg + 4]  = make_float4(r4, r5, r6, r7);
  *(float4*)&Rrow[cg + 8]  = make_float4(r8, r9, r10, r11);
  *(float4*)&Rrow[cg + 12] = make_float4(r12, r13, r14, r15);
}

// ---------------- K4d: cvec = out_w @ pbv + out_b ----------------
__global__ __launch_bounds__(256) void k_cvec(const float* __restrict__ outw,
                                              const float* __restrict__ outb,
                                              const float* __restrict__ pbv,
                                              float* __restrict__ cvec) {
  int o = blockIdx.x * 256 + threadIdx.x;
  int b = blockIdx.y;
  __shared__ float sp[512];
  for (int i = threadIdx.x; i < 512; i += 256) sp[i] = pbv[b * CCH + i];
  __syncthreads();
  float a = outb[o];
  const float* wr_ = outw + (size_t)o * CCH;
  for (int c2 = 0; c2 < 512; ++c2) a += wr_[c2] * sp[c2];
  cvec[b * CCH + o] = a;
}

// ---------------- K5: out = x + M16 @ H + cvec (fp16 MFMA, BK=64 single-buf) -------
__global__ __launch_bounds__(256, 2) void k_out(const f16* __restrict__ M16,
                                                const f16* __restrict__ Ht,
                                                const float* __restrict__ x,
                                                const float* __restrict__ cvec,
                                                float* __restrict__ out) {
  int nt = blockIdx.x;   // 128 n-tiles
  int mt = blockIdx.y;   // 4 o-tiles
  int b = blockIdx.z;
  int m0 = mt * 128, n0 = nt * 128;
  int t = threadIdx.x, lane = t & 63, wid = t >> 6;
  int wr = wid >> 1, wc = wid & 1;
  __shared__ __align__(16) f16 sA[128 * 64];
  __shared__ __align__(16) f16 sB[128 * 64];
  const f16* A = M16 + (size_t)b * CCH * CCH;
  const f16* Bp = Ht + (size_t)b * NTOK * CCH;
  f32x4 acc[4][4] = {};
  int ldsrow = wid * 8 + (lane >> 3);
  int slot = lane & 7;
  int lr = lane & 15, lk = lane >> 4;
  for (int ks = 0; ks < 8; ++ks) {
    int kk0 = ks * 64;
    __syncthreads();
#pragma unroll
    for (int i = 0; i < 4; ++i) {
      int row = ldsrow + i * 32;
      int cA = ((slot ^ (row & 7)) * 8);
      g2l16(A + (size_t)(m0 + row) * CCH + kk0 + cA, &sA[i * 2048 + wid * 512]);
      g2l16(Bp + (size_t)(n0 + row) * CCH + kk0 + cA, &sB[i * 2048 + wid * 512]);
    }
    asm volatile("s_waitcnt vmcnt(0)" ::: "memory");
    __syncthreads();
#pragma unroll
    for (int kk = 0; kk < 2; ++kk) {
      f16x8 af[4], bf[4];
#pragma unroll
      for (int mi = 0; mi < 4; ++mi) {
        int row = wr * 64 + mi * 16 + lr;
        int ks8 = (kk * 4 + lk) ^ (row & 7);
        af[mi] = *(const f16x8*)&sA[row * 64 + ks8 * 8];
      }
#pragma unroll
      for (int ni = 0; ni < 4; ++ni) {
        int row = wc * 64 + ni * 16 + lr;
        int ks8 = (kk * 4 + lk) ^ (row & 7);
        bf[ni] = *(const f16x8*)&sB[row * 64 + ks8 * 8];
      }
#pragma unroll
      for (int mi = 0; mi < 4; ++mi)
#pragma unroll
        for (int ni = 0; ni < 4; ++ni)
          acc[mi][ni] = __builtin_amdgcn_mfma_f32_16x16x32_f16(af[mi], bf[ni], acc[mi][ni], 0, 0, 0);
    }
  }

  const float* xb = x + ((size_t)b * CCH) * NTOK;
  float* ob = out + ((size_t)b * CCH) * NTOK;
#pragma unroll
  for (int mi = 0; mi < 4; ++mi)
#pragma unroll
    for (int j = 0; j < 4; ++j) {
      int o = m0 + wr * 64 + mi * 16 + lk * 4 + j;
      float cv = cvec[b * CCH + o];
      size_t rowoff = (size_t)o * NTOK;
#pragma unroll
      for (int ni = 0; ni < 4; ++ni) {
        int n = n0 + wc * 64 + ni * 16 + lr;
        size_t idx = rowoff + n;
        ob[idx] = xb[idx] + acc[mi][ni][j] + cv;
      }
    }
}

extern "C" void kernel_launch(void* const* d_in, const int* in_sizes, int n_in,
                              void* d_out, int out_size, void* d_ws, size_t ws_size,
                              hipStream_t stream) {
  const float* x    = (const float*)d_in[0];
  const float* gw   = (const float*)d_in[1];
  const float* gb   = (const float*)d_in[2];
  const float* qkvw = (const float*)d_in[3];
  const float* qkvb = (const float*)d_in[4];
  const float* outw = (const float*)d_in[5];
  const float* outb = (const float*)d_in[6];
  int B = in_sizes[0] / (CCH * NTOK);   // 4

  char* ws = (char*)d_ws;
  size_t off = 0;
  f16* H    = (f16*)(ws + off);   off += (size_t)B * CCH * NTOK * 2;   // 64 MiB
  f16* Ht   = (f16*)(ws + off);   off += (size_t)B * NTOK * CCH * 2;   // 64 MiB
  float* G  = (float*)(ws + off); off += (size_t)B * CCH * CCH * 4;    // 4 MiB
  float* T1 = (float*)(ws + off); off += (size_t)B * CCH * CCH * 4;    // 4 MiB
  float* R  = (float*)(ws + off); off += (size_t)B * CCH * CCH * 4;    // 4 MiB
  f16* M16  = (f16*)(ws + off);   off += (size_t)B * CCH * CCH * 2;    // 2 MiB
  float* P  = (float*)(ws + off); off += (size_t)B * NHEAD * 64 * 64 * 4;  // 512 KiB
  float* uvec  = (float*)(ws + off); off += (size_t)B * 1024 * 4;
  float* pbv   = (float*)(ws + off); off += (size_t)B * CCH * 4;
  float* cvec  = (float*)(ws + off); off += (size_t)B * CCH * 4;
  // zero-init region: stats, svec, L (contiguous -> single memset)
  float* stats = (float*)(ws + off); off += (size_t)B * 8 * 2 * 4;
  float* svec  = (float*)(ws + off); off += (size_t)B * CCH * 4;
  float* L     = (float*)(ws + off); off += (size_t)B * NHEAD * 64 * 64 * 4;  // 512 KiB
  size_t zbytes = (size_t)(B * 8 * 2 + B * CCH + B * NHEAD * 64 * 64) * 4;

  hipMemsetAsync(G, 0, (size_t)B * CCH * CCH * 4, stream);
  hipMemsetAsync(stats, 0, zbytes, stream);

  k_stats<<<dim3(32, B * 8), 256, 0, stream>>>(x, stats);
  k_gnorm<<<dim3(64, 8, B), 256, 0, stream>>>(x, gw, gb, stats, H, Ht, svec);
  k_syrk<<<dim3(10, SPLITS, B), 256, 0, stream>>>(H, G);
  k_symm<<<dim3(24, B), 256, 0, stream>>>(G);
  k_sgemm512<false><<<dim3(8, 8, B), 256, 0, stream>>>(qkvw, G, T1,
                                                       (size_t)CCH * CCH, (size_t)CCH * CCH);
  k_uvec<<<dim3(4, B), 256, 0, stream>>>(qkvw, svec, uvec);
  k_logits<<<dim3(8, NHEAD, B), 256, 0, stream>>>(T1, qkvw, L);
  k_softmax<<<dim3(B * NHEAD), 64, 0, stream>>>(L, uvec, qkvb, P, pbv);
  k_pv<<<dim3(8, NHEAD, B), 256, 0, stream>>>(P, qkvw, R);
  k_sgemm512<true><<<dim3(8, 8, B), 256, 0, stream>>>(outw, R, M16,
                                                      (size_t)CCH * CCH, (size_t)CCH * CCH);
  k_cvec<<<dim3(2, B), 256, 0, stream>>>(outw, outb, pbv, cvec);
  k_out<<<dim3(128, 4, B), 256, 0, stream>>>(M16, Ht, x, cvec, (float*)d_out);
}

// Round 10
// 392.842 us; speedup vs baseline: 1.1694x; 1.0731x over previous
//
#include <hip/hip_runtime.h>
#include <hip/hip_fp16.h>

// AttentionBlock3D: channel attention. B=4, C=512, N=T*H*W=16384, 8 heads, d=64.
// Algebraic reduction: result = x + M*H + c, with
//   G = H H^T (per batch, SYMMETRIC -> upper tiles only + k_symm mirror),
//   logits = scale*(Wq G Wk^T + rank-1), P = softmax per head,
//   M = out_w * blockdiag(P) * Wv, c = out_w * blockdiag(P) * bv + out_b.
//
// MFMA kernel geometry (measured-best, R2/R8/R9 ladder):
//   BK=64 (128B rows, 8x16B slots, XOR-swizzle slot^(row&7) => 0 bank conflicts),
//   single LDS buffer (32 KiB), 2 barriers per K-step,
//   __launch_bounds__(256, 2): lb(256,4) packs more blocks/CU and REGRESSES 39%
//   (R8: 118us vs R9: 84us, same code otherwise) - barrier-drain convoying.
//   BK=32 variants (R7) produce 4-way ds_read conflicts; 64KB dbuf (R6) halves occupancy.
// R10: k_out prefetches the x-residual into VGPRs before the K-loop (T14):
//   x-read overlaps MFMA instead of serializing after the last drain.

#define CCH 512
#define NTOK 16384
#define NHEAD 8

typedef _Float16 f16;
typedef _Float16 f16x8 __attribute__((ext_vector_type(8)));
typedef float f32x4 __attribute__((ext_vector_type(4)));

__device__ __forceinline__ void g2l16(const void* g, void* l) {
  __builtin_amdgcn_global_load_lds((const __attribute__((address_space(1))) void*)g,
                                   (__attribute__((address_space(3))) void*)l,
                                   16, 0, 0);
}

// ---------------- K1: GroupNorm stats (sum, sumsq) per (b, group) ----------------
__global__ __launch_bounds__(256) void k_stats(const float* __restrict__ x,
                                               float* __restrict__ stats) {
  int bg = blockIdx.y;          // b*8 + g  (group region is contiguous: 64 rows * NTOK)
  int chunk = blockIdx.x;       // 0..31
  const float4* p = (const float4*)(x + (size_t)bg * (64ull * NTOK)) + (size_t)chunk * 8192;
  float s = 0.f, q = 0.f;
  for (int i = threadIdx.x; i < 8192; i += 256) {
    float4 v = p[i];
    s += v.x + v.y + v.z + v.w;
    q += v.x * v.x + v.y * v.y + v.z * v.z + v.w * v.w;
  }
  for (int off = 32; off; off >>= 1) { s += __shfl_down(s, off); q += __shfl_down(q, off); }
  __shared__ float ls[4], lq[4];
  int wid = threadIdx.x >> 6, lane = threadIdx.x & 63;
  if (lane == 0) { ls[wid] = s; lq[wid] = q; }
  __syncthreads();
  if (threadIdx.x == 0) {
    atomicAdd(&stats[bg * 2 + 0], ls[0] + ls[1] + ls[2] + ls[3]);
    atomicAdd(&stats[bg * 2 + 1], lq[0] + lq[1] + lq[2] + lq[3]);
  }
}

// ---------------- K2: normalize -> H (fp16, [b][c][n]) and Ht (fp16, [b][n][c]), s = H*1 ----
// R10: float4 x loads, ushort4 H stores, channel-major LDS tile (ds_write_b64).
__global__ __launch_bounds__(256) void k_gnorm(const float* __restrict__ x,
                                               const float* __restrict__ gw,
                                               const float* __restrict__ gb,
                                               const float* __restrict__ stats,
                                               f16* __restrict__ H, f16* __restrict__ Ht,
                                               float* __restrict__ svec) {
  int nc = blockIdx.x;   // n chunk (256 tokens)
  int cg = blockIdx.y;   // channel group (64 ch) == GN group
  int b = blockIdx.z;
  int t = threadIdx.x;
  __shared__ f16 T2[64][260];     // [c_local][n_local], 260-half rows (520B: bank stride 2)
  __shared__ float svp[4][64];
  float sum = stats[(b * 8 + cg) * 2], sq = stats[(b * 8 + cg) * 2 + 1];
  const float inv = 1.f / (64.f * (float)NTOK);
  float mean = sum * inv;
  float var = fmaxf(sq * inv - mean * mean, 0.f);
  float rsig = rsqrtf(var + 1e-5f);
  int c0 = cg * 64, n0 = nc * 256;
  int tq = t & 63, rr0 = t >> 6;       // lane owns 4 consecutive tokens; wave owns row set
#pragma unroll
  for (int it = 0; it < 16; ++it) {
    int r = it * 4 + rr0;
    int c = c0 + r;
    float a = gw[c] * rsig;
    float bb = gb[c] - mean * a;
    size_t idx = ((size_t)(b * CCH + c)) * NTOK + n0 + tq * 4;
    float4 xv = *(const float4*)&x[idx];
    f16 hh[4] __attribute__((aligned(8)));
    hh[0] = (f16)(xv.x * a + bb);
    hh[1] = (f16)(xv.y * a + bb);
    hh[2] = (f16)(xv.z * a + bb);
    hh[3] = (f16)(xv.w * a + bb);
    *(uint2*)&H[idx] = *(const uint2*)hh;          // 8B store
    *(uint2*)&T2[r][tq * 4] = *(const uint2*)hh;   // 8B LDS write, 2-bank lane stride
  }
  __syncthreads();
  {  // svec partials: 4 quarter-sums per channel, then combine
    int c = t & 63, q = t >> 6;
    float acc = 0.f;
#pragma unroll
    for (int j = 0; j < 64; ++j) acc += (float)T2[c][q * 64 + j];
    svp[q][c] = acc;
  }
  __syncthreads();
  if (t < 64) {
    atomicAdd(&svec[b * CCH + c0 + t],
              svp[0][t] + svp[1][t] + svp[2][t] + svp[3][t]);
  }
  int s8 = t & 7, nl = t >> 3;        // transpose write-out: 8 threads per Ht row
#pragma unroll
  for (int it = 0; it < 8; ++it) {
    int n = it * 32 + nl;
    f16 g[8] __attribute__((aligned(16)));
#pragma unroll
    for (int j = 0; j < 8; ++j) g[j] = T2[s8 * 8 + j][n];
    *(uint4*)&Ht[((size_t)b * NTOK + n0 + n) * CCH + c0 + s8 * 8] = *(const uint4*)g;
  }
}

// ---------------- K3: G = H H^T, upper tiles, split-K=16, BK=64 single-buf (32KB) ----
#define SPLITS 16
__global__ __launch_bounds__(256, 2) void k_syrk(const f16* __restrict__ H,
                                                 float* __restrict__ G) {
  // 10 upper-triangle tiles of 128x128 over the 512x512 output
  const int TI[10] = {0, 0, 0, 0, 1, 1, 1, 2, 2, 3};
  const int TJ[10] = {0, 1, 2, 3, 1, 2, 3, 2, 3, 3};
  int tile = blockIdx.x;
  int split = blockIdx.y;
  int b = blockIdx.z;
  int ii = TI[tile], jj = TJ[tile];
  int m0 = ii * 128, n0 = jj * 128;
  int t = threadIdx.x, lane = t & 63, wid = t >> 6;
  int wr = wid >> 1, wc = wid & 1;
  __shared__ __align__(16) f16 sA[128 * 64];
  __shared__ __align__(16) f16 sB[128 * 64];
  const f16* Hb = H + (size_t)b * CCH * NTOK;
  int k0 = split * (NTOK / SPLITS);     // 1024 per split
  f32x4 acc[4][4] = {};
  int ldsrow = wid * 8 + (lane >> 3);   // 128B rows: 8 lanes/row
  int slot = lane & 7;                  // 16B slot within row
  int lr = lane & 15, lk = lane >> 4;

  const int NS = (NTOK / SPLITS) / 64;  // 16 K-steps of BK=64
  for (int ks = 0; ks < NS; ++ks) {
    int kk0 = k0 + ks * 64;
    __syncthreads();
#pragma unroll
    for (int i = 0; i < 4; ++i) {
      int row = ldsrow + i * 32;
      int cA = ((slot ^ (row & 7)) * 8);  // pre-swizzled global source column
      g2l16(Hb + (size_t)(m0 + row) * NTOK + kk0 + cA, &sA[i * 2048 + wid * 512]);
      g2l16(Hb + (size_t)(n0 + row) * NTOK + kk0 + cA, &sB[i * 2048 + wid * 512]);
    }
    asm volatile("s_waitcnt vmcnt(0)" ::: "memory");
    __syncthreads();
#pragma unroll
    for (int kk = 0; kk < 2; ++kk) {
      f16x8 af[4], bf[4];
#pragma unroll
      for (int mi = 0; mi < 4; ++mi) {
        int row = wr * 64 + mi * 16 + lr;
        int ks8 = (kk * 4 + lk) ^ (row & 7);
        af[mi] = *(const f16x8*)&sA[row * 64 + ks8 * 8];
      }
#pragma unroll
      for (int ni = 0; ni < 4; ++ni) {
        int row = wc * 64 + ni * 16 + lr;
        int ks8 = (kk * 4 + lk) ^ (row & 7);
        bf[ni] = *(const f16x8*)&sB[row * 64 + ks8 * 8];
      }
#pragma unroll
      for (int mi = 0; mi < 4; ++mi)
#pragma unroll
        for (int ni = 0; ni < 4; ++ni)
          acc[mi][ni] = __builtin_amdgcn_mfma_f32_16x16x32_f16(af[mi], bf[ni], acc[mi][ni], 0, 0, 0);
    }
  }

  float* Gb = G + (size_t)b * CCH * CCH;
#pragma unroll
  for (int mi = 0; mi < 4; ++mi)
#pragma unroll
    for (int j = 0; j < 4; ++j) {
      int rr2 = m0 + wr * 64 + mi * 16 + lk * 4 + j;
#pragma unroll
      for (int ni = 0; ni < 4; ++ni) {
        int cc = n0 + wc * 64 + ni * 16 + lr;
        atomicAdd(&Gb[(size_t)rr2 * CCH + cc], acc[mi][ni][j]);   // coalesced rows only
      }
    }
}

// ---------------- K3b: mirror upper off-diag tiles to lower triangle ----------------
__global__ __launch_bounds__(256) void k_symm(float* __restrict__ G) {
  // 6 off-diag 128-tiles x 4 subtiles of 64x64 = 24 subtiles per batch
  const int TI6[6] = {0, 0, 0, 1, 1, 2};
  const int TJ6[6] = {1, 2, 3, 2, 3, 3};
  int bx = blockIdx.x;               // 0..23
  int b = blockIdx.y;
  int t6 = bx >> 2, sub = bx & 3;
  int ib = TI6[t6] * 2 + (sub >> 1); // source 64-row block
  int jb = TJ6[t6] * 2 + (sub & 1);  // source 64-col block
  float* Gb = G + (size_t)b * CCH * CCH;
  __shared__ float s[64][65];
  int t = threadIdx.x;
  int r = t >> 2, cg = (t & 3) * 16;
  const float* src = &Gb[(size_t)(ib * 64 + r) * CCH + jb * 64 + cg];
#pragma unroll
  for (int k = 0; k < 4; ++k) {
    float4 v = *(const float4*)(src + k * 4);
    s[r][cg + k * 4 + 0] = v.x; s[r][cg + k * 4 + 1] = v.y;
    s[r][cg + k * 4 + 2] = v.z; s[r][cg + k * 4 + 3] = v.w;
  }
  __syncthreads();
  float* dst = &Gb[(size_t)(jb * 64 + r) * CCH + ib * 64 + cg];
#pragma unroll
  for (int k = 0; k < 4; ++k) {
    float4 v;
    v.x = s[cg + k * 4 + 0][r]; v.y = s[cg + k * 4 + 1][r];
    v.z = s[cg + k * 4 + 2][r]; v.w = s[cg + k * 4 + 3][r];
    *(float4*)(dst + k * 4) = v;
  }
}

// ---------------- K4a/K4c: fp32 512x512x512 GEMM, C[b] = A @ B[b] ----------------
template <bool HALF_OUT>
__global__ __launch_bounds__(256) void k_sgemm512(const float* __restrict__ A,
                                                  const float* __restrict__ Bm,
                                                  void* __restrict__ Cv,
                                                  size_t strideB, size_t strideC) {
  int n0 = blockIdx.x * 64, m0 = blockIdx.y * 64, b = blockIdx.z;
  const float* Bb = Bm + (size_t)b * strideB;
  int t = threadIdx.x;
  int rm = t >> 4, rn = t & 15;
  __shared__ float sA[16][68];  // [k][m] transposed
  __shared__ float sB[16][68];  // [k][n]
  float acc[4][4] = {};
  for (int k0 = 0; k0 < 512; k0 += 16) {
#pragma unroll
    for (int i = 0; i < 4; ++i) {
      int idx = i * 256 + t;
      int mrow = idx >> 4, kc = idx & 15;
      sA[kc][mrow] = A[(size_t)(m0 + mrow) * CCH + k0 + kc];
      int krow = idx >> 6, ncc = idx & 63;
      sB[krow][ncc] = Bb[(size_t)(k0 + krow) * CCH + n0 + ncc];
    }
    __syncthreads();
#pragma unroll
    for (int k = 0; k < 16; ++k) {
      float4 a4 = *(const float4*)&sA[k][rm * 4];
      float4 b4 = *(const float4*)&sB[k][rn * 4];
      acc[0][0] += a4.x * b4.x; acc[0][1] += a4.x * b4.y; acc[0][2] += a4.x * b4.z; acc[0][3] += a4.x * b4.w;
      acc[1][0] += a4.y * b4.x; acc[1][1] += a4.y * b4.y; acc[1][2] += a4.y * b4.z; acc[1][3] += a4.y * b4.w;
      acc[2][0] += a4.z * b4.x; acc[2][1] += a4.z * b4.y; acc[2][2] += a4.z * b4.z; acc[2][3] += a4.z * b4.w;
      acc[3][0] += a4.w * b4.x; acc[3][1] += a4.w * b4.y; acc[3][2] += a4.w * b4.z; acc[3][3] += a4.w * b4.w;
    }
    __syncthreads();
  }
  if constexpr (HALF_OUT) {
    f16* Cc = ((f16*)Cv) + (size_t)b * strideC;
#pragma unroll
    for (int i = 0; i < 4; ++i)
#pragma unroll
      for (int j = 0; j < 4; ++j)
        Cc[(size_t)(m0 + rm * 4 + i) * CCH + n0 + rn * 4 + j] = (f16)acc[i][j];
  } else {
    float* Cc = ((float*)Cv) + (size_t)b * strideC;
#pragma unroll
    for (int i = 0; i < 4; ++i)
#pragma unroll
      for (int j = 0; j < 4; ++j)
        Cc[(size_t)(m0 + rm * 4 + i) * CCH + n0 + rn * 4 + j] = acc[i][j];
  }
}

// ---------------- K4b-1: uvec[b][0:512]=Wq@s, [512:1024]=Wk@s (4 lanes/output) ----
__global__ __launch_bounds__(256) void k_uvec(const float* __restrict__ qkvw,
                                              const float* __restrict__ svec,
                                              float* __restrict__ uvec) {
  int o = blockIdx.x * 64 + (threadIdx.x >> 2);   // grid.x = 16
  int l = threadIdx.x & 3;
  int b = blockIdx.y;
  __shared__ float ss[512];
  for (int i = threadIdx.x; i < 512; i += 256) ss[i] = svec[b * CCH + i];
  __syncthreads();
  const float* wr_ = qkvw + (size_t)o * CCH + l * 128;
  const float* sp = ss + l * 128;
  float a = 0.f;
#pragma unroll
  for (int i = 0; i < 32; ++i) {
    float4 w = *(const float4*)&wr_[i * 4];
    a += w.x * sp[i * 4] + w.y * sp[i * 4 + 1] + w.z * sp[i * 4 + 2] + w.w * sp[i * 4 + 3];
  }
  a += __shfl_down(a, 2);
  a += __shfl_down(a, 1);
  if (l == 0) uvec[b * 1024 + o] = a;
}

// ---------------- K4b-2: L[b,h] += T1_h[64xK-chunk] @ Wk_h^T (split-K, atomics) ----
__global__ __launch_bounds__(256) void k_logits(const float* __restrict__ T1,
                                                const float* __restrict__ qkvw,
                                                float* __restrict__ L) {
  int kc = blockIdx.x;     // 8 chunks of 64 k
  int h = blockIdx.y, b = blockIdx.z;
  int t = threadIdx.x;
  int h64 = h * 64, k0 = kc * 64;
  __shared__ float sT[64][68];   // [d][k]
  __shared__ float sW[64][68];   // [k][e]
#pragma unroll
  for (int i = 0; i < 16; ++i) {
    int idx = i * 256 + t;
    int r = idx >> 6, c = idx & 63;
    sT[r][c] = T1[((size_t)b * CCH + h64 + r) * CCH + k0 + c];
    sW[c][r] = qkvw[(size_t)(512 + h64 + r) * CCH + k0 + c];
  }
  __syncthreads();
  int d = t >> 2, eg = (t & 3) * 16;
  float acc[16] = {};
  for (int k = 0; k < 64; ++k) {
    float a = sT[d][k];
    float4 w0 = *(const float4*)&sW[k][eg];
    float4 w1 = *(const float4*)&sW[k][eg + 4];
    float4 w2 = *(const float4*)&sW[k][eg + 8];
    float4 w3 = *(const float4*)&sW[k][eg + 12];
    acc[0] += a * w0.x;  acc[1] += a * w0.y;  acc[2] += a * w0.z;  acc[3] += a * w0.w;
    acc[4] += a * w1.x;  acc[5] += a * w1.y;  acc[6] += a * w1.z;  acc[7] += a * w1.w;
    acc[8] += a * w2.x;  acc[9] += a * w2.y;  acc[10] += a * w2.z; acc[11] += a * w2.w;
    acc[12] += a * w3.x; acc[13] += a * w3.y; acc[14] += a * w3.z; acc[15] += a * w3.w;
  }
  float* Lrow = &L[(((size_t)b * NHEAD + h) * 64 + d) * 64 + eg];
#pragma unroll
  for (int i = 0; i < 16; ++i) atomicAdd(&Lrow[i], acc[i]);
}

// ---------------- K4b-3: softmax rows + rank-1 bias terms -> P, pbv ----------------
__global__ __launch_bounds__(64) void k_softmax(const float* __restrict__ L,
                                                const float* __restrict__ uvec,
                                                const float* __restrict__ qkvb,
                                                float* __restrict__ P,
                                                float* __restrict__ pbv) {
  int bh = blockIdx.x;           // b*8 + h
  int b = bh >> 3, h = bh & 7;
  int d = threadIdx.x;           // 0..63
  int h64 = h * 64;
  __shared__ float sbk[64], sbv[64], suk[64];
  sbk[d] = qkvb[512 + h64 + d];
  sbv[d] = qkvb[1024 + h64 + d];
  suk[d] = uvec[b * 1024 + 512 + h64 + d];
  __syncthreads();
  float uq = uvec[b * 1024 + h64 + d];
  float bq = qkvb[h64 + d];
  float l[64];
  const float* Lr = &L[((size_t)bh * 64 + d) * 64];
  float m = -1e30f;
#pragma unroll
  for (int e = 0; e < 64; ++e) {
    float v = (Lr[e] + uq * sbk[e] + bq * suk[e] + 16384.f * bq * sbk[e]) * 0.125f;
    l[e] = v;
    m = fmaxf(m, v);
  }
  float sum = 0.f;
#pragma unroll
  for (int e = 0; e < 64; ++e) { float p = expf(l[e] - m); l[e] = p; sum += p; }
  float r = 1.f / sum, pb = 0.f;
  float* Pr = &P[((size_t)bh * 64 + d) * 64];
#pragma unroll
  for (int e = 0; e < 64; ++e) { float p = l[e] * r; Pr[e] = p; pb += p * sbv[e]; }
  pbv[b * CCH + h64 + d] = pb;
}

// ---------------- K4b-4: R[b, h64+d, c] = sum_e P[b,h,d,e] Wv[h64+e][c] ----------
__global__ __launch_bounds__(256) void k_pv(const float* __restrict__ P,
                                            const float* __restrict__ qkvw,
                                            float* __restrict__ R) {
  int ct = blockIdx.x;     // 8 c-tiles of 64
  int h = blockIdx.y, b = blockIdx.z;
  int t = threadIdx.x;
  int h64 = h * 64, c0 = ct * 64;
  __shared__ float sP[64][68];   // [d][e]
  __shared__ float sW[64][68];   // [e][c]
#pragma unroll
  for (int i = 0; i < 16; ++i) {
    int idx = i * 256 + t;
    int r = idx >> 6, c = idx & 63;
    sP[r][c] = P[(((size_t)b * NHEAD + h) * 64 + r) * 64 + c];
    sW[r][c] = qkvw[(size_t)(1024 + h64 + r) * CCH + c0 + c];
  }
  __syncthreads();
  int d = t >> 2, cg = (t & 3) * 16;
  float r0 = 0, r1 = 0, r2 = 0, r3 = 0, r4 = 0, r5 = 0, r6 = 0, r7 = 0;
  float r8 = 0, r9 = 0, r10 = 0, r11 = 0, r12 = 0, r13 = 0, r14 = 0, r15 = 0;
  for (int e = 0; e < 64; ++e) {
    float p = sP[d][e];
    float4 w0 = *(const float4*)&sW[e][cg];
    float4 w1 = *(const float4*)&sW[e][cg + 4];
    float4 w2 = *(const float4*)&sW[e][cg + 8];
    float4 w3 = *(const float4*)&sW[e][cg + 12];
    r0 += p * w0.x;  r1 += p * w0.y;  r2 += p * w0.z;  r3 += p * w0.w;
    r4 += p * w1.x;  r5 += p * w1.y;  r6 += p * w1.z;  r7 += p * w1.w;
    r8 += p * w2.x;  r9 += p * w2.y;  r10 += p * w2.z; r11 += p * w2.w;
    r12 += p * w3.x; r13 += p * w3.y; r14 += p * w3.z; r15 += p * w3.w;
  }
  float* Rrow = &R[((size_t)b * CCH + h64 + d) * CCH + c0];
  *(float4*)&Rrow[cg + 0]  = make_float4(r0, r1, r2, r3);
  *(float4*)&Rrow[cg + 4]  = make_float4(r4, r5, r6, r7);
  *(float4*)&Rrow[cg + 8]  = make_float4(r8, r9, r10, r11);
  *(float4*)&Rrow[cg + 12] = make_float4(r12, r13, r14, r15);
}

// ---------------- K4d: cvec = out_w @ pbv + out_b (4 lanes/output) ----------------
__global__ __launch_bounds__(256) void k_cvec(const float* __restrict__ outw,
                                              const float* __restrict__ outb,
                                              const float* __restrict__ pbv,
                                              float* __restrict__ cvec) {
  int o = blockIdx.x * 64 + (threadIdx.x >> 2);   // grid.x = 8
  int l = threadIdx.x & 3;
  int b = blockIdx.y;
  __shared__ float sp[512];
  for (int i = threadIdx.x; i < 512; i += 256) sp[i] = pbv[b * CCH + i];
  __syncthreads();
  const float* wr_ = outw + (size_t)o * CCH + l * 128;
  const float* spp = sp + l * 128;
  float a = 0.f;
#pragma unroll
  for (int i = 0; i < 32; ++i) {
    float4 w = *(const float4*)&wr_[i * 4];
    a += w.x * spp[i * 4] + w.y * spp[i * 4 + 1] + w.z * spp[i * 4 + 2] + w.w * spp[i * 4 + 3];
  }
  a += __shfl_down(a, 2);
  a += __shfl_down(a, 1);
  if (l == 0) cvec[b * CCH + o] = a + outb[o];
}

// ---------------- K5: out = x + M16 @ H + cvec (fp16 MFMA, BK=64, x prefetch) -----
__global__ __launch_bounds__(256, 2) void k_out(const f16* __restrict__ M16,
                                                const f16* __restrict__ Ht,
                                                const float* __restrict__ x,
                                                const float* __restrict__ cvec,
                                                float* __restrict__ out) {
  int nt = blockIdx.x;   // 128 n-tiles
  int mt = blockIdx.y;   // 4 o-tiles
  int b = blockIdx.z;
  int m0 = mt * 128, n0 = nt * 128;
  int t = threadIdx.x, lane = t & 63, wid = t >> 6;
  int wr = wid >> 1, wc = wid & 1;
  __shared__ __align__(16) f16 sA[128 * 64];
  __shared__ __align__(16) f16 sB[128 * 64];
  const f16* A = M16 + (size_t)b * CCH * CCH;
  const f16* Bp = Ht + (size_t)b * NTOK * CCH;
  const float* xb = x + ((size_t)b * CCH) * NTOK;
  f32x4 acc[4][4] = {};
  int ldsrow = wid * 8 + (lane >> 3);
  int slot = lane & 7;
  int lr = lane & 15, lk = lane >> 4;

  // T14: prefetch the x-residual into VGPRs; loads complete under the K-loop.
  float xv[4][4][4];
#pragma unroll
  for (int mi = 0; mi < 4; ++mi)
#pragma unroll
    for (int j = 0; j < 4; ++j) {
      size_t rowoff = (size_t)(m0 + wr * 64 + mi * 16 + lk * 4 + j) * NTOK;
#pragma unroll
      for (int ni = 0; ni < 4; ++ni)
        xv[mi][j][ni] = xb[rowoff + n0 + wc * 64 + ni * 16 + lr];
    }

  for (int ks = 0; ks < 8; ++ks) {
    int kk0 = ks * 64;
    __syncthreads();
#pragma unroll
    for (int i = 0; i < 4; ++i) {
      int row = ldsrow + i * 32;
      int cA = ((slot ^ (row & 7)) * 8);
      g2l16(A + (size_t)(m0 + row) * CCH + kk0 + cA, &sA[i * 2048 + wid * 512]);
      g2l16(Bp + (size_t)(n0 + row) * CCH + kk0 + cA, &sB[i * 2048 + wid * 512]);
    }
    asm volatile("s_waitcnt vmcnt(0)" ::: "memory");
    __syncthreads();
#pragma unroll
    for (int kk = 0; kk < 2; ++kk) {
      f16x8 af[4], bf[4];
#pragma unroll
      for (int mi = 0; mi < 4; ++mi) {
        int row = wr * 64 + mi * 16 + lr;
        int ks8 = (kk * 4 + lk) ^ (row & 7);
        af[mi] = *(const f16x8*)&sA[row * 64 + ks8 * 8];
      }
#pragma unroll
      for (int ni = 0; ni < 4; ++ni) {
        int row = wc * 64 + ni * 16 + lr;
        int ks8 = (kk * 4 + lk) ^ (row & 7);
        bf[ni] = *(const f16x8*)&sB[row * 64 + ks8 * 8];
      }
#pragma unroll
      for (int mi = 0; mi < 4; ++mi)
#pragma unroll
        for (int ni = 0; ni < 4; ++ni)
          acc[mi][ni] = __builtin_amdgcn_mfma_f32_16x16x32_f16(af[mi], bf[ni], acc[mi][ni], 0, 0, 0);
    }
  }

  float* ob = out + ((size_t)b * CCH) * NTOK;
#pragma unroll
  for (int mi = 0; mi < 4; ++mi)
#pragma unroll
    for (int j = 0; j < 4; ++j) {
      int o = m0 + wr * 64 + mi * 16 + lk * 4 + j;
      float cv = cvec[b * CCH + o];
      size_t rowoff = (size_t)o * NTOK;
#pragma unroll
      for (int ni = 0; ni < 4; ++ni) {
        int n = n0 + wc * 64 + ni * 16 + lr;
        ob[rowoff + n] = xv[mi][j][ni] + acc[mi][ni][j] + cv;
      }
    }
}

extern "C" void kernel_launch(void* const* d_in, const int* in_sizes, int n_in,
                              void* d_out, int out_size, void* d_ws, size_t ws_size,
                              hipStream_t stream) {
  const float* x    = (const float*)d_in[0];
  const float* gw   = (const float*)d_in[1];
  const float* gb   = (const float*)d_in[2];
  const float* qkvw = (const float*)d_in[3];
  const float* qkvb = (const float*)d_in[4];
  const float* outw = (const float*)d_in[5];
  const float* outb = (const float*)d_in[6];
  int B = in_sizes[0] / (CCH * NTOK);   // 4

  char* ws = (char*)d_ws;
  size_t off = 0;
  f16* H    = (f16*)(ws + off);   off += (size_t)B * CCH * NTOK * 2;   // 64 MiB
  f16* Ht   = (f16*)(ws + off);   off += (size_t)B * NTOK * CCH * 2;   // 64 MiB
  float* G  = (float*)(ws + off); off += (size_t)B * CCH * CCH * 4;    // 4 MiB
  float* T1 = (float*)(ws + off); off += (size_t)B * CCH * CCH * 4;    // 4 MiB
  float* R  = (float*)(ws + off); off += (size_t)B * CCH * CCH * 4;    // 4 MiB
  f16* M16  = (f16*)(ws + off);   off += (size_t)B * CCH * CCH * 2;    // 2 MiB
  float* P  = (float*)(ws + off); off += (size_t)B * NHEAD * 64 * 64 * 4;  // 512 KiB
  float* uvec  = (float*)(ws + off); off += (size_t)B * 1024 * 4;
  float* pbv   = (float*)(ws + off); off += (size_t)B * CCH * 4;
  float* cvec  = (float*)(ws + off); off += (size_t)B * CCH * 4;
  // zero-init region: stats, svec, L (contiguous -> single memset)
  float* stats = (float*)(ws + off); off += (size_t)B * 8 * 2 * 4;
  float* svec  = (float*)(ws + off); off += (size_t)B * CCH * 4;
  float* L     = (float*)(ws + off); off += (size_t)B * NHEAD * 64 * 64 * 4;  // 512 KiB
  size_t zbytes = (size_t)(B * 8 * 2 + B * CCH + B * NHEAD * 64 * 64) * 4;

  hipMemsetAsync(G, 0, (size_t)B * CCH * CCH * 4, stream);
  hipMemsetAsync(stats, 0, zbytes, stream);

  k_stats<<<dim3(32, B * 8), 256, 0, stream>>>(x, stats);
  k_gnorm<<<dim3(64, 8, B), 256, 0, stream>>>(x, gw, gb, stats, H, Ht, svec);
  k_syrk<<<dim3(10, SPLITS, B), 256, 0, stream>>>(H, G);
  k_symm<<<dim3(24, B), 256, 0, stream>>>(G);
  k_sgemm512<false><<<dim3(8, 8, B), 256, 0, stream>>>(qkvw, G, T1,
                                                       (size_t)CCH * CCH, (size_t)CCH * CCH);
  k_uvec<<<dim3(16, B), 256, 0, stream>>>(qkvw, svec, uvec);
  k_logits<<<dim3(8, NHEAD, B), 256, 0, stream>>>(T1, qkvw, L);
  k_softmax<<<dim3(B * NHEAD), 64, 0, stream>>>(L, uvec, qkvb, P, pbv);
  k_pv<<<dim3(8, NHEAD, B), 256, 0, stream>>>(P, qkvw, R);
  k_sgemm512<true><<<dim3(8, 8, B), 256, 0, stream>>>(outw, R, M16,
                                                      (size_t)CCH * CCH, (size_t)CCH * CCH);
  k_cvec<<<dim3(8, B), 256, 0, stream>>>(outw, outb, pbv, cvec);
  k_out<<<dim3(128, 4, B), 256, 0, stream>>>(M16, Ht, x, cvec, (float*)d_out);
}